// Round 1
// baseline (205.738 us; speedup 1.0000x reference)
//
#include <hip/hip_runtime.h>

#define BATCH    8192
#define FEAT     256
#define NCLASS   100000
#define EPS_C    1e-6f

#define NC_ELEMS (NCLASS * FEAT)          // 25,600,000 floats
#define NVEC     (NC_ELEMS / 4)           // 6,400,000 float4s
#define COPY_BLOCKS (NVEC / 256)          // 25,000 blocks

// Build per-class linked lists. head memset to -1 beforehand.
__global__ void build_kernel(const int* __restrict__ target,
                             int* __restrict__ head,
                             int* __restrict__ next) {
    int b = blockIdx.x * blockDim.x + threadIdx.x;
    if (b < BATCH) next[b] = atomicExch(&head[target[b]], b);
}

// Pure streaming copy of centers -> out shifted by +1 float (out[0] = loss slot).
// Shift handled in-register: aligned float4 load, __shfl_up for the cross-lane
// element, tiny LDS only for the 3 cross-wave seams, one extra scalar load for
// the cross-block seam. Touched rows get stale values here; update_kernel
// rewrites those rows entirely afterward (stream-ordered), so no list walking
// and no head[] checks on the streaming path.
__global__ void copy_kernel(const float* __restrict__ centers,
                            float* __restrict__ out) {
    __shared__ float wtail[4];            // last element of each wave's chunk
    int t = threadIdx.x;
    int w = t >> 6;
    int l = t & 63;
    size_t i = (size_t)blockIdx.x * 256 + t;          // float4 index
    float4 c4 = ((const float4*)centers)[i];          // centers[4i .. 4i+3]

    float pw = __shfl_up(c4.w, 1, 64);                // centers[4i-1] for l>=1
    if (l == 63) wtail[w] = c4.w;
    __syncthreads();
    if (l == 0) {
        if (w > 0) {
            pw = wtail[w - 1];
        } else if (blockIdx.x > 0) {
            pw = centers[(size_t)blockIdx.x * 1024 - 1];
        } else {
            pw = 0.0f;                    // out[0] = loss slot; finalize overwrites
        }
    }
    float4 ov = {pw, c4.x, c4.y, c4.z};   // out[4i..4i+3] = centers[4i-1..4i+2]
    ((float4*)out)[i] = ov;

    // tail: out[NC_ELEMS] = centers[NC_ELEMS-1]
    if (blockIdx.x == COPY_BLOCKS - 1 && t == 255) out[NC_ELEMS] = c4.w;
}

// One wave per SAMPLE. The wave whose sample is the head of its class list
// owns the class: walks the list, computes per-sample loss partials and the
// updated row, overwrites the (shifted) row in out. All branch conditions are
// wave-uniform. ~7.9k of 8.2k waves active; ~24 MB total traffic.
__global__ void update_kernel(const float* __restrict__ centers,
                              const float* __restrict__ features,
                              const int* __restrict__ target,
                              const int* __restrict__ head,
                              const int* __restrict__ next,
                              float* __restrict__ partials,
                              float* __restrict__ out) {
    int wv = (blockIdx.x * blockDim.x + threadIdx.x) >> 6;   // sample id 0..8191
    int l  = threadIdx.x & 63;
    int r  = target[wv];
    if (head[r] != wv) return;            // only the head sample's wave proceeds

    const float4 c4 = ((const float4*)(centers + (size_t)r * FEAT))[l];
    float4 sumf = {0.f, 0.f, 0.f, 0.f};
    int n = 0;
    for (int s = wv; s != -1; s = next[s]) {
        float4 f4 = ((const float4*)(features + (size_t)s * FEAT))[l];
        sumf.x += f4.x; sumf.y += f4.y; sumf.z += f4.z; sumf.w += f4.w;
        float dx = c4.x - f4.x, dy = c4.y - f4.y;
        float dz = c4.z - f4.z, dw = c4.w - f4.w;
        float sq = dx*dx + dy*dy + dz*dz + dw*dw;
        #pragma unroll
        for (int off = 32; off > 0; off >>= 1) sq += __shfl_down(sq, off, 64);
        if (l == 0) partials[s] = sq;     // each sample is in exactly one list
        n++;
    }
    float nf  = (float)n;
    float inv = 1.0f / (nf + EPS_C);
    // new = c - (n*c - sum_f)/(n+eps)
    float nx = c4.x - (nf * c4.x - sumf.x) * inv;
    float ny = c4.y - (nf * c4.y - sumf.y) * inv;
    float nz = c4.z - (nf * c4.z - sumf.z) * inv;
    float nw = c4.w - (nf * c4.w - sumf.w) * inv;

    // shifted row write (out + 1 breaks 16B alignment -> 4 scalar dwords/lane;
    // only ~7.9k rows = 8 MB, negligible vs the streaming copy)
    float* orow = out + 1 + (size_t)r * FEAT + 4 * l;
    orow[0] = nx; orow[1] = ny; orow[2] = nz; orow[3] = nw;
}

__global__ void finalize_kernel(const float* __restrict__ partials,
                                float* __restrict__ out0) {
    float s = 0.0f;
    for (int i = threadIdx.x; i < BATCH; i += 256) s += partials[i];
    #pragma unroll
    for (int off = 32; off > 0; off >>= 1) s += __shfl_down(s, off, 64);
    __shared__ float red[4];
    int wave = threadIdx.x >> 6;
    int lane = threadIdx.x & 63;
    if (lane == 0) red[wave] = s;
    __syncthreads();
    if (threadIdx.x == 0) {
        out0[0] = (red[0] + red[1] + red[2] + red[3]) / (float)(BATCH * FEAT);
    }
}

extern "C" void kernel_launch(void* const* d_in, const int* in_sizes, int n_in,
                              void* d_out, int out_size, void* d_ws, size_t ws_size,
                              hipStream_t stream) {
    const float* features = (const float*)d_in[0];
    const int*   target   = (const int*)d_in[1];
    const float* centers  = (const float*)d_in[2];
    float* out = (float*)d_out;

    int*   head     = (int*)d_ws;                  // 100000 ints
    int*   next     = head + NCLASS;               // 8192 ints
    float* partials = (float*)(next + BATCH);      // 8192 floats

    hipMemsetAsync(head, 0xFF, NCLASS * sizeof(int), stream);
    build_kernel<<<(BATCH + 255) / 256, 256, 0, stream>>>(target, head, next);
    copy_kernel<<<COPY_BLOCKS, 256, 0, stream>>>(centers, out);
    update_kernel<<<BATCH / 4, 256, 0, stream>>>(centers, features, target,
                                                 head, next, partials, out);
    finalize_kernel<<<1, 256, 0, stream>>>(partials, out);
}